// Round 9
// baseline (104.122 us; speedup 1.0000x reference)
//
#include <hip/hip_runtime.h>
#include <stdint.h>

#define N_ROWS  8192
#define DIM     512            // elements = bytes (fp8)
#define BI      64             // i-rows per block (z1, output axis)
#define JS      4              // j splits
#define JR      (N_ROWS / JS)  // 2048 j-rows per block
#define JT      128            // j-tile rows
#define NTL     (JR / JT)      // 16 j-tiles per block
#define NGRP    (NTL * 4)      // 64 groups (each 128 j x 128 K-bytes = 16 KB)
#define THREADS 512
#define SCL16   0x7B7B7B7BU    // e8m0 123 = 2^-4 per operand (undoes data x16)

typedef __attribute__((ext_vector_type(16))) float f32x16;
typedef __attribute__((ext_vector_type(8)))  int   i32x8;
typedef __attribute__((ext_vector_type(4)))  int   i32x4;

#define BAR()    { asm volatile("" ::: "memory"); __builtin_amdgcn_s_barrier(); asm volatile("" ::: "memory"); }
#define WAITV(n) asm volatile("s_waitcnt vmcnt(" #n ")" ::: "memory")
#define WAITL0() asm volatile("s_waitcnt lgkmcnt(0)" ::: "memory")

#define MFMA8(a, b, c) __builtin_amdgcn_mfma_scale_f32_32x32x64_f8f6f4( \
    (a), (b), (c), 0, 0, 0, SCL16, 0, SCL16)

// manual RNE float -> OCP e4m3fn (|f| <= 16 guaranteed; no NaN/inf inputs)
__device__ __forceinline__ unsigned int f2e4m3(float f) {
    unsigned int u = __float_as_uint(f);
    unsigned int s = (u >> 24) & 0x80u;
    float a = fabsf(f);
    if (a < 0.015625f) {                     // subnormal: step 2^-9
        int q = (int)rintf(a * 512.0f);      // 0..8 (8 rolls into min-normal)
        return s | (unsigned int)q;
    }
    unsigned int mag = u & 0x7fffffffu;
    mag += 0x7FFFFu + ((mag >> 20) & 1u);    // RNE into 3-bit mantissa
    return s | ((mag >> 20) - 960u);         // (E-120)<<3 | M3
}

// async global -> LDS, 16 B per lane (wave-uniform LDS base + lane*16)
__device__ __forceinline__ void gload_lds16(const void* g, void* l) {
    __builtin_amdgcn_global_load_lds(
        (const __attribute__((address_space(1))) unsigned int*)g,
        (__attribute__((address_space(3))) unsigned int*)l,
        16, 0, 0);
}

// ---------------- Kernel 1: L2-normalize rows + cast to fp8 (x16) ----------
__global__ __launch_bounds__(256) void norm_cast_kernel(
    const float* __restrict__ z1, const float* __restrict__ z2,
    unsigned char* __restrict__ o1, unsigned char* __restrict__ o2)
{
    int row  = blockIdx.x * 4 + (threadIdx.x >> 6);
    int lane = threadIdx.x & 63;
    const float* src;
    unsigned char* dst;
    if (row < N_ROWS) { src = z1 + (size_t)row * DIM;            dst = o1 + (size_t)row * DIM; }
    else              { src = z2 + (size_t)(row - N_ROWS) * DIM; dst = o2 + (size_t)(row - N_ROWS) * DIM; }

    const float4* s4 = (const float4*)src + lane * 2;
    float4 a = s4[0], b = s4[1];
    float ss = a.x*a.x + a.y*a.y + a.z*a.z + a.w*a.w
             + b.x*b.x + b.y*b.y + b.z*b.z + b.w*b.w;
#pragma unroll
    for (int x = 1; x < 64; x <<= 1) ss += __shfl_xor(ss, x);
    float inv = 16.0f / fmaxf(sqrtf(ss), 1e-12f);   // x16 into e4m3 normal range

    uint2 o;
    o.x = f2e4m3(a.x*inv) | (f2e4m3(a.y*inv) << 8) | (f2e4m3(a.z*inv) << 16) | (f2e4m3(a.w*inv) << 24);
    o.y = f2e4m3(b.x*inv) | (f2e4m3(b.y*inv) << 8) | (f2e4m3(b.z*inv) << 16) | (f2e4m3(b.w*inv) << 24);
    *(uint2*)(dst + lane * 8) = o;
}

// ---------------- Kernel 2: persistent-i, streamed-j MX-fp8 sim GEMM -------
// Block = 64 i-rows x 2048 j-rows. z1 (I) lives in REGISTERS for the whole
// kernel (iF[8], 64 VGPR); z2 (J) streams through a 4-buffer LDS ring in
// 16 KB groups (128 j x 128 K). den/sm/sq accumulate in registers across all
// j-tiles; one tiny global write per block at the end.
// 8 waves = 4 j-quarters (wq) x 2 i-halves (wh); wave = 32j x 32i per MFMA.
__global__ __launch_bounds__(THREADS, 4) void fused_sim_kernel(
    const unsigned char* __restrict__ A,    // z1 fp8 [8192][512]
    const unsigned char* __restrict__ B,    // z2 fp8 [8192][512]
    const int* __restrict__ ids,
    float* __restrict__ partial)            // [3][JS][N_ROWS]
{
    __shared__ alignas(128) unsigned char Js[4][16384];   // 64 KB ring
    __shared__ int   idj[JR];                             // 8 KB
    __shared__ float red[4][2][3][32];                    // 3 KB

    const int tid  = threadIdx.x;
    const int lane = tid & 63;
    const int wid  = tid >> 6;
    const int wq   = wid >> 1;                 // 0..3  j-quarter (32 rows)
    const int wh   = wid & 1;                  // 0..1  i-half (32 rows)

    // XCD-pinned j-split: all blocks on an XCD stream the same 1 MB z2 slice
    const int flat = blockIdx.x;               // 512 blocks
    const int xcd  = flat & 7;
    const int js   = xcd & 3;                  // j-split 0..3
    const int iblk = (flat >> 3) * 2 + (xcd >> 2);   // 0..127
    const int brow = iblk * BI;
    const int jb0  = js * JR;

    // ---- prologue: whole-K I-fragments into registers (z1 never in LDS)
    const int irow = brow + wh * 32 + (lane & 31);
    const unsigned char* ibase = A + (size_t)irow * DIM + (lane >> 5) * 32;
    i32x8 iF[8];
#pragma unroll
    for (int kc = 0; kc < 8; ++kc) {
        i32x4 lo = *(const i32x4*)(ibase + kc * 64);
        i32x4 hi = *(const i32x4*)(ibase + kc * 64 + 16);
        iF[kc] = __builtin_shufflevector(lo, hi, 0, 1, 2, 3, 4, 5, 6, 7);
    }
    const int rid = ids[irow];
    {
        i32x4 v = *(const i32x4*)&ids[jb0 + tid * 4];
        *(i32x4*)&idj[tid * 4] = v;
    }
    WAITV(0); WAITL0();        // clean vmcnt before the counted staging loop

    // stage group g: j-rows [tile*128,+128), K-bytes [q*128,+128) -> buf g&3
    auto stage = [&](int g) {
        const int buf  = g & 3;
        const int tile = g >> 2;
        const int q    = g & 3;
        const unsigned char* base = B + (size_t)(jb0 + tile * JT) * DIM + q * 128;
#pragma unroll
        for (int h2 = 0; h2 < 2; ++h2) {
            int seg   = h2 * 512 + tid;
            int chunk = seg >> 9, rem = seg & 511;
            int f = rem >> 7, hh = (rem >> 6) & 1, ln = rem & 63;
            int row = f * 32 + (ln & 31);
            int kb  = (ln >> 5) * 32 + hh * 16;
            gload_lds16(base + (size_t)row * DIM + chunk * 64 + kb,
                        &Js[buf][seg * 16]);
        }
    };
    // J-frag: operand row = lane&31, k-bytes = (lane>>5)*32 + 0..31
    auto ldJ = [&](int buf, int c) -> i32x8 {
        const unsigned char* p = &Js[buf][c * 8192 + wq * 2048 + lane * 16];
        i32x4 lo = *(const i32x4*)p;
        i32x4 hi = *(const i32x4*)(p + 1024);
        return __builtin_shufflevector(lo, hi, 0, 1, 2, 3, 4, 5, 6, 7);
    };

    f32x16 acc = (f32x16)0.f;
    float dp = 0.f, sp = 0.f, qp = 0.f;
    const int jrow0 = wq * 32 + 4 * (lane >> 5);

    stage(0); stage(1); stage(2);      // 6 vmem instr
    WAITV(4);                          // group 0 landed; 1,2 in flight
    BAR();

    for (int tile = 0; tile < NTL - 1; ++tile) {
#pragma unroll
        for (int q = 0; q < 4; ++q) {           // buf == q (tile*4 ≡ 0 mod 4)
            const int g = tile * 4 + q;
            stage(g + 3);                       // into buf (q+3)&3, freed last BAR
            i32x8 j0 = ldJ(q, 0);
            i32x8 j1 = ldJ(q, 1);
            __builtin_amdgcn_s_setprio(1);
            acc = MFMA8(j0, iF[2 * q],     acc);
            acc = MFMA8(j1, iF[2 * q + 1], acc);
            __builtin_amdgcn_s_setprio(0);
            if (q == 3) {                       // j-tile done: fold into stats
                const int jb = tile * JT + jrow0;
#pragma unroll
                for (int r = 0; r < 16; ++r) {
                    const int cid = idj[jb + (r & 3) + 8 * (r >> 2)];
                    float e = __expf(acc[r] * 10.0f - 10.0f);   // exp(sim-10)
                    dp += e;
                    sp += (rid == cid) ? e : 0.f;
                    qp += (rid == cid) ? 0.f : e * e;
                }
                acc = (f32x16)0.f;
            }
            WAITV(4);                           // group g+1 landed; g+2,g+3 fly
            BAR();
        }
    }
    // ---- peeled last tile (groups 60..63), draining waits
    {
        const int tile = NTL - 1;
        stage(63);
        { i32x8 j0 = ldJ(0, 0), j1 = ldJ(0, 1);
          __builtin_amdgcn_s_setprio(1);
          acc = MFMA8(j0, iF[0], acc); acc = MFMA8(j1, iF[1], acc);
          __builtin_amdgcn_s_setprio(0);
          WAITV(4); BAR(); }
        { i32x8 j0 = ldJ(1, 0), j1 = ldJ(1, 1);
          __builtin_amdgcn_s_setprio(1);
          acc = MFMA8(j0, iF[2], acc); acc = MFMA8(j1, iF[3], acc);
          __builtin_amdgcn_s_setprio(0);
          WAITV(2); BAR(); }
        { i32x8 j0 = ldJ(2, 0), j1 = ldJ(2, 1);
          __builtin_amdgcn_s_setprio(1);
          acc = MFMA8(j0, iF[4], acc); acc = MFMA8(j1, iF[5], acc);
          __builtin_amdgcn_s_setprio(0);
          WAITV(0); BAR(); }
        { i32x8 j0 = ldJ(3, 0), j1 = ldJ(3, 1);
          __builtin_amdgcn_s_setprio(1);
          acc = MFMA8(j0, iF[6], acc); acc = MFMA8(j1, iF[7], acc);
          __builtin_amdgcn_s_setprio(0);
          const int jb = tile * JT + jrow0;
#pragma unroll
          for (int r = 0; r < 16; ++r) {
              const int cid = idj[jb + (r & 3) + 8 * (r >> 2)];
              float e = __expf(acc[r] * 10.0f - 10.0f);
              dp += e;
              sp += (rid == cid) ? e : 0.f;
              qp += (rid == cid) ? 0.f : e * e;
          } }
    }

    // ---- block reduce: fold lh halves, then the 4 j-quarters via LDS
    dp += __shfl_xor(dp, 32);
    sp += __shfl_xor(sp, 32);
    qp += __shfl_xor(qp, 32);
    if (lane < 32) {
        red[wq][wh][0][lane] = dp;
        red[wq][wh][1][lane] = sp;
        red[wq][wh][2][lane] = qp;
    }
    __syncthreads();
    if (tid < 192) {
        const int li = tid & 31;
        const int s  = (tid >> 5) % 3;
        const int hh = tid / 96;
        float v = red[0][hh][s][li] + red[1][hh][s][li]
                + red[2][hh][s][li] + red[3][hh][s][li];
        partial[((size_t)s * JS + js) * N_ROWS + brow + hh * 32 + li] = v;
    }
}

// ---------------- Kernel 3: per-row loss, per-block sums ----------------
__global__ __launch_bounds__(256) void reduce_kernel(
    const float* __restrict__ partial, float* __restrict__ blocksum)
{
    int row = blockIdx.x * 256 + threadIdx.x;
    float den = 0.f, sm = 0.f, sq = 0.f;
#pragma unroll
    for (int j = 0; j < JS; ++j) {
        den += partial[((size_t)0 * JS + j) * N_ROWS + row];
        sm  += partial[((size_t)1 * JS + j) * N_ROWS + row];
        sq  += partial[((size_t)2 * JS + j) * N_ROWS + row];
    }
    float num  = sm + sq / den;
    float loss = -logf(num / (den + 1e-8f) + 1e-8f);
#pragma unroll
    for (int x = 1; x < 64; x <<= 1) loss += __shfl_xor(loss, x);
    __shared__ float p[4];
    if ((threadIdx.x & 63) == 0) p[threadIdx.x >> 6] = loss;
    __syncthreads();
    if (threadIdx.x == 0) blocksum[blockIdx.x] = p[0] + p[1] + p[2] + p[3];
}

__global__ void final_kernel(const float* __restrict__ blocksum, float* __restrict__ out)
{
    float v = (threadIdx.x < 32) ? blocksum[threadIdx.x] : 0.f;
#pragma unroll
    for (int x = 1; x < 64; x <<= 1) v += __shfl_xor(v, x);
    if (threadIdx.x == 0) out[0] = v * (1.0f / (float)N_ROWS);
}

extern "C" void kernel_launch(void* const* d_in, const int* in_sizes, int n_in,
                              void* d_out, int out_size, void* d_ws, size_t ws_size,
                              hipStream_t stream) {
    const float* z1  = (const float*)d_in[0];
    const float* z2  = (const float*)d_in[1];
    const int*   ids = (const int*)d_in[2];

    char* ws = (char*)d_ws;
    unsigned char* z1q = (unsigned char*)ws;                                 // 4 MB
    unsigned char* z2q = (unsigned char*)(ws + (size_t)N_ROWS * DIM);        // 4 MB
    float* partial  = (float*)(ws + (size_t)2 * N_ROWS * DIM);               // 384 KB
    float* blocksum = partial + (size_t)3 * JS * N_ROWS;                     // 128 B

    norm_cast_kernel<<<dim3(4096), dim3(256), 0, stream>>>(z1, z2, z1q, z2q);
    fused_sim_kernel<<<dim3(512), dim3(THREADS), 0, stream>>>(z1q, z2q, ids, partial);
    reduce_kernel<<<dim3(32), dim3(256), 0, stream>>>(partial, blocksum);
    final_kernel<<<dim3(1), dim3(64), 0, stream>>>(blocksum, (float*)d_out);
}

// Round 10
// 84.646 us; speedup vs baseline: 1.2301x; 1.2301x over previous
//
#include <hip/hip_runtime.h>
#include <stdint.h>

#define N_ROWS  8192
#define DIM     512            // elements = bytes (fp8)
#define BJ      256            // tile rows of z2 (j, reduction axis)
#define BI      256            // tile rows of z1 (i, output axis)
#define BK      64             // K-bytes per tile
#define NT      (DIM / BK)     // 8 K-tiles
#define NBUF    3              // LDS ring buffers (prefetch distance 2)
#define NCB     32             // j-blocks (8192/256)
#define THREADS 512
#define SCL16   0x7B7B7B7BU    // e8m0 123 = 2^-4 per operand (undoes data x16)

typedef __attribute__((ext_vector_type(16))) float f32x16;
typedef __attribute__((ext_vector_type(8)))  int   i32x8;
typedef __attribute__((ext_vector_type(4)))  int   i32x4;

#define BAR()    { asm volatile("" ::: "memory"); __builtin_amdgcn_s_barrier(); asm volatile("" ::: "memory"); }
#define WAITV(n) asm volatile("s_waitcnt vmcnt(" #n ")" ::: "memory")
#define WAITL0() asm volatile("s_waitcnt lgkmcnt(0)" ::: "memory")

#define MFMA8(a, b, c) __builtin_amdgcn_mfma_scale_f32_32x32x64_f8f6f4( \
    (a), (b), (c), 0, 0, 0, SCL16, 0, SCL16)

// manual RNE float -> OCP e4m3fn (|f| <= 16 guaranteed; no NaN/inf inputs)
__device__ __forceinline__ unsigned int f2e4m3(float f) {
    unsigned int u = __float_as_uint(f);
    unsigned int s = (u >> 24) & 0x80u;
    float a = fabsf(f);
    if (a < 0.015625f) {                     // subnormal: step 2^-9
        int q = (int)rintf(a * 512.0f);      // 0..8 (8 rolls into min-normal)
        return s | (unsigned int)q;
    }
    unsigned int mag = u & 0x7fffffffu;
    mag += 0x7FFFFu + ((mag >> 20) & 1u);    // RNE into 3-bit mantissa
    return s | ((mag >> 20) - 960u);         // (E-120)<<3 | M3
}

// async global -> LDS, 16 B per lane (wave-uniform LDS base + lane*16)
__device__ __forceinline__ void gload_lds16(const void* g, void* l) {
    __builtin_amdgcn_global_load_lds(
        (const __attribute__((address_space(1))) unsigned int*)g,
        (__attribute__((address_space(3))) unsigned int*)l,
        16, 0, 0);
}

// ---------------- Kernel 1: L2-normalize rows + cast to fp8 (x16) ----------
__global__ __launch_bounds__(256) void norm_cast_kernel(
    const float* __restrict__ z1, const float* __restrict__ z2,
    unsigned char* __restrict__ o1, unsigned char* __restrict__ o2)
{
    int row  = blockIdx.x * 4 + (threadIdx.x >> 6);
    int lane = threadIdx.x & 63;
    const float* src;
    unsigned char* dst;
    if (row < N_ROWS) { src = z1 + (size_t)row * DIM;            dst = o1 + (size_t)row * DIM; }
    else              { src = z2 + (size_t)(row - N_ROWS) * DIM; dst = o2 + (size_t)(row - N_ROWS) * DIM; }

    const float4* s4 = (const float4*)src + lane * 2;
    float4 a = s4[0], b = s4[1];
    float ss = a.x*a.x + a.y*a.y + a.z*a.z + a.w*a.w
             + b.x*b.x + b.y*b.y + b.z*b.z + b.w*b.w;
#pragma unroll
    for (int x = 1; x < 64; x <<= 1) ss += __shfl_xor(ss, x);
    float inv = 16.0f / fmaxf(sqrtf(ss), 1e-12f);   // x16 into e4m3 normal range

    uint2 o;
    o.x = f2e4m3(a.x*inv) | (f2e4m3(a.y*inv) << 8) | (f2e4m3(a.z*inv) << 16) | (f2e4m3(a.w*inv) << 24);
    o.y = f2e4m3(b.x*inv) | (f2e4m3(b.y*inv) << 8) | (f2e4m3(b.z*inv) << 16) | (f2e4m3(b.w*inv) << 24);
    *(uint2*)(dst + lane * 8) = o;
}

// ---------------- Kernel 2: 256x256 MX-fp8 sim GEMM, m201 schedule ---------
// Swapped operands: acc[jb][ib] = mfma(Jfrag, Ifrag): output ROW axis = j
// (z2 row, reduction axis, register-indexed), COL axis = i (z1 row, lane).
// 8 waves = 4 j-quarters (wj, 64 rows) x 2 i-halves (wi, 128 rows).
// Per tile per wave: 12 ds_read_b128 -> stage t+2 (4 instr) -> BAR ->
// lgkmcnt(0) -> setprio(1) -> 8 MFMA -> setprio(0) -> WAITV(4) -> BAR.
// NBUF=3 ring, prefetch distance 2, vmcnt never 0 until the tail.
__global__ __launch_bounds__(THREADS, 2) void fused_sim_kernel(
    const unsigned char* __restrict__ A,    // z1 fp8 [8192][512]
    const unsigned char* __restrict__ B,    // z2 fp8 [8192][512]
    const int* __restrict__ ids,
    float* __restrict__ partial)            // [3][NCB][N_ROWS]
{
    __shared__ alignas(128) unsigned char Js[NBUF][BJ * BK];  // 48 KB (z2)
    __shared__ alignas(128) unsigned char Is[NBUF][BI * BK];  // 48 KB (z1)
    __shared__ int   idi[BI], idj[BJ];                        // 2 KB
    __shared__ float red[4][3][BI];                           // 12 KB

    const int tid  = threadIdx.x;
    const int lane = tid & 63;
    const int wid  = tid >> 6;
    const int wj   = wid >> 1;                 // 0..3  j-quarter (64 rows)
    const int wi   = wid & 1;                  // 0..1  i-half (128 rows)

    // XCD chunking: each XCD owns a 4-wide bx (j-block) stripe; bx fastest.
    const int flat = blockIdx.x;
    const int xcd  = flat & 7;
    const int s    = flat >> 3;                // 0..127
    const int bx   = xcd * 4 + (s & 3);        // 0..31  (j block)
    const int by   = s >> 2;                   // 0..31  (i block)
    const int brow = by * BI;                  // z1 base row
    const int bcol = bx * BJ;                  // z2 base row

    // id loads FIRST (compiler drains their vmcnt before the ds_write,
    // which is before any staging -> staging vmcnt counts stay clean)
    if (tid < BI)  idi[tid] = ids[brow + tid];
    else           idj[tid - BI] = ids[bcol + (tid - BI)];

    // stage one 256-row x 64-B tile side (16 KB): 2 instr/thread.
    // seg -> (f = seg>>7, h = (seg>>6)&1, ln = seg&63); LDS addr = seg*16;
    // global: row = f*32 + (ln&31), kbyte = (ln>>5)*32 + h*16
    auto stageJ = [&](int buf, int k0) {
#pragma unroll
        for (int g = 0; g < 2; ++g) {
            int seg = g * 512 + tid;
            int f = seg >> 7, h = (seg >> 6) & 1, ln = seg & 63;
            int row = f * 32 + (ln & 31);
            int kb  = (ln >> 5) * 32 + h * 16;
            gload_lds16(B + (size_t)(bcol + row) * DIM + k0 + kb, &Js[buf][seg * 16]);
        }
    };
    auto stageI = [&](int buf, int k0) {
#pragma unroll
        for (int g = 0; g < 2; ++g) {
            int seg = g * 512 + tid;
            int f = seg >> 7, h = (seg >> 6) & 1, ln = seg & 63;
            int row = f * 32 + (ln & 31);
            int kb  = (ln >> 5) * 32 + h * 16;
            gload_lds16(A + (size_t)(brow + row) * DIM + k0 + kb, &Is[buf][seg * 16]);
        }
    };

    // frag reads: operand row = lane&31, k-bytes = (lane>>5)*32 + 0..31,
    // as two lane-linear 16 B halves (conflict-free, r8-validated).
    auto ldJ = [&](int buf, int jb) -> i32x8 {
        const unsigned char* p = &Js[buf][(wj * 2 + jb) * 2048 + lane * 16];
        i32x4 lo = *(const i32x4*)p;
        i32x4 hi = *(const i32x4*)(p + 1024);
        return __builtin_shufflevector(lo, hi, 0, 1, 2, 3, 4, 5, 6, 7);
    };
    auto ldI = [&](int buf, int ib) -> i32x8 {
        const unsigned char* p = &Is[buf][(wi * 4 + ib) * 2048 + lane * 16];
        i32x4 lo = *(const i32x4*)p;
        i32x4 hi = *(const i32x4*)(p + 1024);
        return __builtin_shufflevector(lo, hi, 0, 1, 2, 3, 4, 5, 6, 7);
    };

    f32x16 acc[2][4];
#pragma unroll
    for (int m = 0; m < 2; ++m)
#pragma unroll
        for (int n = 0; n < 4; ++n) acc[m][n] = (f32x16)0.f;

    // prologue: stage tiles 0 and 1 (4 vmem instr each)
    stageJ(0, 0);  stageI(0, 0);
    stageJ(1, BK); stageI(1, BK);
    WAITL0();                      // id ds_writes visible after BAR
    WAITV(4);                      // tile 0 landed; tile 1's 4 in flight
    BAR();

#pragma unroll
    for (int t = 0; t < NT; ++t) {
        const int buf = t % NBUF;
        // ---- ds-reads for THIS tile (12 x b128) ----
        i32x8 j0 = ldJ(buf, 0), j1 = ldJ(buf, 1);
        i32x8 i0 = ldI(buf, 0), i1 = ldI(buf, 1), i2 = ldI(buf, 2), i3 = ldI(buf, 3);
        // ---- issue stage for tile t+2 (4 instr) ----
        if (t + 2 < NT) {
            const int nb = (t + 2) % NBUF;
            stageJ(nb, (t + 2) * BK);
            stageI(nb, (t + 2) * BK);
        }
        BAR();
        WAITL0();
        __builtin_amdgcn_s_setprio(1);
        acc[0][0] = MFMA8(j0, i0, acc[0][0]);
        acc[0][1] = MFMA8(j0, i1, acc[0][1]);
        acc[0][2] = MFMA8(j0, i2, acc[0][2]);
        acc[0][3] = MFMA8(j0, i3, acc[0][3]);
        acc[1][0] = MFMA8(j1, i0, acc[1][0]);
        acc[1][1] = MFMA8(j1, i1, acc[1][1]);
        acc[1][2] = MFMA8(j1, i2, acc[1][2]);
        acc[1][3] = MFMA8(j1, i3, acc[1][3]);
        __builtin_amdgcn_s_setprio(0);
        // counted tile-boundary wait: t+1 resident, t+2's 4 stay in flight
        if (t < NT - 2)      { WAITV(4); BAR(); }
        else if (t < NT - 1) { WAITV(0); BAR(); }
    }

    // ---- epilogue: 32x32 C/D: col(i)=lane&31, row(j)=(reg&3)+8*(reg>>2)+4*(lane>>5)
    const int li = lane & 31, lh = lane >> 5;
    int   rid[4];
    float dp[4], sp[4], qp[4];
#pragma unroll
    for (int ib = 0; ib < 4; ++ib) {
        rid[ib] = idi[wi * 128 + ib * 32 + li];
        dp[ib] = 0.f; sp[ib] = 0.f; qp[ib] = 0.f;
    }
#pragma unroll
    for (int jb = 0; jb < 2; ++jb) {
#pragma unroll
        for (int r = 0; r < 16; ++r) {
            const int j   = wj * 64 + jb * 32 + (r & 3) + 8 * (r >> 2) + 4 * lh;
            const int cid = idj[j];
#pragma unroll
            for (int ib = 0; ib < 4; ++ib) {
                float v = acc[jb][ib][r];
                float e = __expf(v * 10.0f - 10.0f);   // exp(sim - 10)
                dp[ib] += e;
                sp[ib] += (rid[ib] == cid) ? e : 0.f;
                qp[ib] += (rid[ib] == cid) ? 0.f : e * e;
            }
        }
    }
#pragma unroll
    for (int ib = 0; ib < 4; ++ib) {
        dp[ib] += __shfl_xor(dp[ib], 32);
        sp[ib] += __shfl_xor(sp[ib], 32);
        qp[ib] += __shfl_xor(qp[ib], 32);
    }
    if (lane < 32) {
#pragma unroll
        for (int ib = 0; ib < 4; ++ib) {
            const int i = wi * 128 + ib * 32 + li;
            red[wj][0][i] = dp[ib];
            red[wj][1][i] = sp[ib];
            red[wj][2][i] = qp[ib];
        }
    }
    __syncthreads();
    if (tid < BI) {
#pragma unroll
        for (int s2 = 0; s2 < 3; ++s2) {
            float v = red[0][s2][tid] + red[1][s2][tid] + red[2][s2][tid] + red[3][s2][tid];
            partial[((size_t)s2 * NCB + bx) * N_ROWS + brow + tid] = v;
        }
    }
}

// ---------------- Kernel 3: per-row loss, per-block sums ----------------
__global__ __launch_bounds__(256) void reduce_kernel(
    const float* __restrict__ partial, float* __restrict__ blocksum)
{
    int row = blockIdx.x * 256 + threadIdx.x;
    float den = 0.f, sm = 0.f, sq = 0.f;
#pragma unroll 4
    for (int cb = 0; cb < NCB; ++cb) {
        den += partial[((size_t)0 * NCB + cb) * N_ROWS + row];
        sm  += partial[((size_t)1 * NCB + cb) * N_ROWS + row];
        sq  += partial[((size_t)2 * NCB + cb) * N_ROWS + row];
    }
    float num  = sm + sq / den;
    float loss = -logf(num / (den + 1e-8f) + 1e-8f);
#pragma unroll
    for (int x = 1; x < 64; x <<= 1) loss += __shfl_xor(loss, x);
    __shared__ float p[4];
    if ((threadIdx.x & 63) == 0) p[threadIdx.x >> 6] = loss;
    __syncthreads();
    if (threadIdx.x == 0) blocksum[blockIdx.x] = p[0] + p[1] + p[2] + p[3];
}

__global__ void final_kernel(const float* __restrict__ blocksum, float* __restrict__ out)
{
    float v = (threadIdx.x < 32) ? blocksum[threadIdx.x] : 0.f;
#pragma unroll
    for (int x = 1; x < 64; x <<= 1) v += __shfl_xor(v, x);
    if (threadIdx.x == 0) out[0] = v * (1.0f / (float)N_ROWS);
}

extern "C" void kernel_launch(void* const* d_in, const int* in_sizes, int n_in,
                              void* d_out, int out_size, void* d_ws, size_t ws_size,
                              hipStream_t stream) {
    const float* z1  = (const float*)d_in[0];
    const float* z2  = (const float*)d_in[1];
    const int*   ids = (const int*)d_in[2];

    char* ws = (char*)d_ws;
    unsigned char* z1q = (unsigned char*)ws;                                 // 4 MB
    unsigned char* z2q = (unsigned char*)(ws + (size_t)N_ROWS * DIM);        // 4 MB
    float* partial  = (float*)(ws + (size_t)2 * N_ROWS * DIM);               // 3 MB
    float* blocksum = partial + (size_t)3 * NCB * N_ROWS;                    // 128 B

    norm_cast_kernel<<<dim3(4096), dim3(256), 0, stream>>>(z1, z2, z1q, z2q);
    fused_sim_kernel<<<dim3(1024), dim3(THREADS), 0, stream>>>(z1q, z2q, ids, partial);
    reduce_kernel<<<dim3(32), dim3(256), 0, stream>>>(partial, blocksum);
    final_kernel<<<dim3(1), dim3(64), 0, stream>>>(blocksum, (float*)d_out);
}

// Round 11
// 81.343 us; speedup vs baseline: 1.2800x; 1.0406x over previous
//
#include <hip/hip_runtime.h>
#include <stdint.h>

#define N_ROWS  8192
#define DIM     512            // elements = bytes (fp8)
#define BM      256            // tile M = N = 256
#define BK      64             // K-bytes per tile
#define NT      (DIM / BK)     // 8 K-tiles
#define NBUF    4              // LDS ring buffers
#define TB      (BM * BK)      // 16 KB per tile side
#define NCB     32             // column blocks (8192/256)
#define THREADS 512
#define SCL16   0x7B7B7B7BU    // e8m0 123 = 2^-4 per operand (undoes data x16)

typedef __attribute__((ext_vector_type(16))) float f32x16;
typedef __attribute__((ext_vector_type(8)))  int   i32x8;
typedef __attribute__((ext_vector_type(4)))  int   i32x4;

#define BAR()    { asm volatile("" ::: "memory"); __builtin_amdgcn_s_barrier(); asm volatile("" ::: "memory"); }
#define WAITV(n) asm volatile("s_waitcnt vmcnt(" #n ")" ::: "memory")
#define WAITL0() asm volatile("s_waitcnt lgkmcnt(0)" ::: "memory")

#define MFMA8(a, b, c) __builtin_amdgcn_mfma_scale_f32_32x32x64_f8f6f4( \
    (a), (b), (c), 0, 0, 0, SCL16, 0, SCL16)

// manual RNE float -> OCP e4m3fn (|f| <= 16 guaranteed; no NaN/inf inputs)
__device__ __forceinline__ unsigned int f2e4m3(float f) {
    unsigned int u = __float_as_uint(f);
    unsigned int s = (u >> 24) & 0x80u;
    float a = fabsf(f);
    if (a < 0.015625f) {                     // subnormal: step 2^-9
        int q = (int)rintf(a * 512.0f);      // 0..8 (8 rolls into min-normal)
        return s | (unsigned int)q;
    }
    unsigned int mag = u & 0x7fffffffu;
    mag += 0x7FFFFu + ((mag >> 20) & 1u);    // RNE into 3-bit mantissa
    return s | ((mag >> 20) - 960u);         // (E-120)<<3 | M3
}

// async global -> LDS, 16 B per lane (wave-uniform LDS base + lane*16)
__device__ __forceinline__ void gload_lds16(const void* g, void* l) {
    __builtin_amdgcn_global_load_lds(
        (const __attribute__((address_space(1))) unsigned int*)g,
        (__attribute__((address_space(3))) unsigned int*)l,
        16, 0, 0);
}

// ---------------- Kernel 1: L2-normalize rows + cast to fp8 (x16) ----------
__global__ __launch_bounds__(256) void norm_cast_kernel(
    const float* __restrict__ z1, const float* __restrict__ z2,
    unsigned char* __restrict__ o1, unsigned char* __restrict__ o2)
{
    int row  = blockIdx.x * 4 + (threadIdx.x >> 6);
    int lane = threadIdx.x & 63;
    const float* src;
    unsigned char* dst;
    if (row < N_ROWS) { src = z1 + (size_t)row * DIM;            dst = o1 + (size_t)row * DIM; }
    else              { src = z2 + (size_t)(row - N_ROWS) * DIM; dst = o2 + (size_t)(row - N_ROWS) * DIM; }

    const float4* s4 = (const float4*)src + lane * 2;
    float4 a = s4[0], b = s4[1];
    float ss = a.x*a.x + a.y*a.y + a.z*a.z + a.w*a.w
             + b.x*b.x + b.y*b.y + b.z*b.z + b.w*b.w;
#pragma unroll
    for (int x = 1; x < 64; x <<= 1) ss += __shfl_xor(ss, x);
    float inv = 16.0f / fmaxf(sqrtf(ss), 1e-12f);   // x16 into e4m3 normal range

    uint2 o;
    o.x = f2e4m3(a.x*inv) | (f2e4m3(a.y*inv) << 8) | (f2e4m3(a.z*inv) << 16) | (f2e4m3(a.w*inv) << 24);
    o.y = f2e4m3(b.x*inv) | (f2e4m3(b.y*inv) << 8) | (f2e4m3(b.z*inv) << 16) | (f2e4m3(b.w*inv) << 24);
    *(uint2*)(dst + lane * 8) = o;
}

// ---------------- Kernel 2: fused 256x256 MX-fp8 sim GEMM ------------------
// EXACT round-6 schedule (best measured: reg-pipelined frag reads, NBUF=4,
// counted WAITV(2), 1 barrier/tile, stage split across alpha/beta phases)
// with ONLY the LDS layout changed to the conflict-free
// [frag32][half][lane][16B] form validated in r7/r8/r10.
// Swapped operands: acc[jb][ib] = mfma(Jfrag, Ifrag): output ROW axis = j
// (z2 row, reduction axis, register-indexed), COL axis = i (z1 row, lane).
__global__ __launch_bounds__(THREADS, 2) void fused_sim_kernel(
    const unsigned char* __restrict__ A,    // z1 fp8 [8192][512]
    const unsigned char* __restrict__ B,    // z2 fp8 [8192][512]
    const int* __restrict__ ids,
    float* __restrict__ partial)            // [3][NCB][N_ROWS]
{
    __shared__ alignas(128) unsigned char Js[NBUF][TB];   // 64 KB (J = z2)
    __shared__ alignas(128) unsigned char Is[NBUF][TB];   // 64 KB (I = z1)
    __shared__ int   idi[BM], idj[BM];                    // 2 KB
    __shared__ float red[2][3][BM];                       // 6 KB

    const int tid  = threadIdx.x;
    const int lane = tid & 63;
    const int wid  = tid >> 6;
    const int wr   = wid >> 2;                 // 0..1  (j half: 128 rows, 4 frags)
    const int wc   = wid & 3;                  // 0..3  (i quarter: 64 rows, 2 frags)

    // 2D XCD chunking: each XCD owns a 4-wide bx stripe; by sweeps inside.
    const int flat = blockIdx.x;
    const int xcd  = flat & 7;
    const int s    = flat >> 3;
    const int bx   = xcd * 4 + (s & 3);        // 0..31  (j block)
    const int by   = s >> 2;                   // 0..31  (i block)
    const int brow = by * BM;                  // z1 base row (i)
    const int bcol = bx * BM;                  // z2 base row (j)

    if (tid < BM) idi[tid] = ids[brow + tid];
    else          idj[tid - BM] = ids[bcol + (tid - BM)];
    WAITL0();

    // stage one 256x64B tile side (16 KB): 2 instr/thread, conflict-free
    // layout: seg -> (f = seg>>7, h = (seg>>6)&1, ln = seg&63); addr = seg*16
    // global: row = f*32 + (ln&31), kbyte = (ln>>5)*32 + h*16
    auto stageJ = [&](int buf, int k0) {
#pragma unroll
        for (int g = 0; g < 2; ++g) {
            int seg = g * 512 + tid;
            int f = seg >> 7, h = (seg >> 6) & 1, ln = seg & 63;
            int row = f * 32 + (ln & 31);
            int kb  = (ln >> 5) * 32 + h * 16;
            gload_lds16(B + (size_t)(bcol + row) * DIM + k0 + kb, &Js[buf][seg * 16]);
        }
    };
    auto stageI = [&](int buf, int k0) {
#pragma unroll
        for (int g = 0; g < 2; ++g) {
            int seg = g * 512 + tid;
            int f = seg >> 7, h = (seg >> 6) & 1, ln = seg & 63;
            int row = f * 32 + (ln & 31);
            int kb  = (ln >> 5) * 32 + h * 16;
            gload_lds16(A + (size_t)(brow + row) * DIM + k0 + kb, &Is[buf][seg * 16]);
        }
    };

    // frag reads: operand row = lane&31, k-bytes = (lane>>5)*32 + 0..31,
    // stored as two lane-linear 16 B halves (conflict-free).
    auto ldJ = [&](int buf, int jb) -> i32x8 {
        const unsigned char* p = &Js[buf][(wr * 4 + jb) * 2048 + lane * 16];
        i32x4 lo = *(const i32x4*)p;
        i32x4 hi = *(const i32x4*)(p + 1024);
        return __builtin_shufflevector(lo, hi, 0, 1, 2, 3, 4, 5, 6, 7);
    };
    auto ldI = [&](int buf, int ib) -> i32x8 {
        const unsigned char* p = &Is[buf][(wc * 2 + ib) * 2048 + lane * 16];
        i32x4 lo = *(const i32x4*)p;
        i32x4 hi = *(const i32x4*)(p + 1024);
        return __builtin_shufflevector(lo, hi, 0, 1, 2, 3, 4, 5, 6, 7);
    };

    f32x16 acc[4][2];
#pragma unroll
    for (int m = 0; m < 4; ++m)
#pragma unroll
        for (int n = 0; n < 2; ++n) acc[m][n] = (f32x16)0.f;

    i32x8 jf[2][4], iF[2][2];

    // prologue: stage tiles 0,1 (4 instrs each side-pair)
    stageI(0, 0);   stageJ(0, 0);
    stageI(1, BK);  stageJ(1, BK);
    WAITV(4);                      // tile 0 landed; tile 1's 4 in flight
    BAR();
    jf[0][0] = ldJ(0, 0); jf[0][1] = ldJ(0, 1);
    iF[0][0] = ldI(0, 0); iF[0][1] = ldI(0, 1);

#pragma unroll
    for (int t = 0; t < NT; ++t) {
        const int p   = t & 1, q = p ^ 1;
        const int cur = t & 3;
        const int nb2 = (t + 2) & 3;
        const int k2  = (t + 2) * BK;

        // ---- phase alpha: read j2,j3[t]; stage I(t+2); MFMA (j0,j1)x(i0,i1)
        jf[p][2] = ldJ(cur, 2); jf[p][3] = ldJ(cur, 3);
        if (t + 2 < NT) stageI(nb2, k2);
        __builtin_amdgcn_s_setprio(1);
        acc[0][0] = MFMA8(jf[p][0], iF[p][0], acc[0][0]);
        acc[0][1] = MFMA8(jf[p][0], iF[p][1], acc[0][1]);
        acc[1][0] = MFMA8(jf[p][1], iF[p][0], acc[1][0]);
        acc[1][1] = MFMA8(jf[p][1], iF[p][1], acc[1][1]);
        __builtin_amdgcn_s_setprio(0);

        // ---- phase beta: counted wait for tile t+1, read its front frags,
        //      stage J(t+2), MFMA (j2,j3)x(i0,i1)
        if (t < NT - 2) { WAITV(2); } else { WAITV(0); }
        BAR();
        if (t + 1 < NT) {
            const int nxt = (t + 1) & 3;
            jf[q][0] = ldJ(nxt, 0); jf[q][1] = ldJ(nxt, 1);
            iF[q][0] = ldI(nxt, 0); iF[q][1] = ldI(nxt, 1);
        }
        if (t + 2 < NT) stageJ(nb2, k2);
        __builtin_amdgcn_s_setprio(1);
        acc[2][0] = MFMA8(jf[p][2], iF[p][0], acc[2][0]);
        acc[2][1] = MFMA8(jf[p][2], iF[p][1], acc[2][1]);
        acc[3][0] = MFMA8(jf[p][3], iF[p][0], acc[3][0]);
        acc[3][1] = MFMA8(jf[p][3], iF[p][1], acc[3][1]);
        __builtin_amdgcn_s_setprio(0);
    }

    // ---- epilogue: 32x32 C/D layout: col(i)=lane&31, row(j)=(reg&3)+8*(reg>>2)+4*(lane>>5)
    const int li = lane & 31, lh = lane >> 5;
    const int rid0 = idi[wc * 64 + li];
    const int rid1 = idi[wc * 64 + 32 + li];
    float dp0 = 0.f, sp0 = 0.f, qp0 = 0.f, dp1 = 0.f, sp1 = 0.f, qp1 = 0.f;
#pragma unroll
    for (int jb = 0; jb < 4; ++jb) {
#pragma unroll
        for (int reg = 0; reg < 16; ++reg) {
            int j   = wr * 128 + jb * 32 + (reg & 3) + 8 * (reg >> 2) + 4 * lh;
            int cid = idj[j];
            float v0 = acc[jb][0][reg], v1 = acc[jb][1][reg];
            float e0 = __expf(v0 * 10.0f - 10.0f);   // exp(sim - 10)
            float e1 = __expf(v1 * 10.0f - 10.0f);
            dp0 += e0; dp1 += e1;
            sp0 += (rid0 == cid) ? e0 : 0.f;  qp0 += (rid0 == cid) ? 0.f : e0 * e0;
            sp1 += (rid1 == cid) ? e1 : 0.f;  qp1 += (rid1 == cid) ? 0.f : e1 * e1;
        }
    }
    dp0 += __shfl_xor(dp0, 32); sp0 += __shfl_xor(sp0, 32); qp0 += __shfl_xor(qp0, 32);
    dp1 += __shfl_xor(dp1, 32); sp1 += __shfl_xor(sp1, 32); qp1 += __shfl_xor(qp1, 32);
    if (lane < 32) {
        red[wr][0][wc * 64 + li]      = dp0;
        red[wr][1][wc * 64 + li]      = sp0;
        red[wr][2][wc * 64 + li]      = qp0;
        red[wr][0][wc * 64 + 32 + li] = dp1;
        red[wr][1][wc * 64 + 32 + li] = sp1;
        red[wr][2][wc * 64 + 32 + li] = qp1;
    }
    __syncthreads();
    if (tid < BM) {
#pragma unroll
        for (int s2 = 0; s2 < 3; ++s2) {
            float v = red[0][s2][tid] + red[1][s2][tid];
            partial[((size_t)s2 * NCB + bx) * N_ROWS + brow + tid] = v;
        }
    }
}

// ---------------- Kernel 3: per-row loss, per-block sums ----------------
__global__ __launch_bounds__(256) void reduce_kernel(
    const float* __restrict__ partial, float* __restrict__ blocksum)
{
    int row = blockIdx.x * 256 + threadIdx.x;
    float den = 0.f, sm = 0.f, sq = 0.f;
#pragma unroll 4
    for (int cb = 0; cb < NCB; ++cb) {
        den += partial[((size_t)0 * NCB + cb) * N_ROWS + row];
        sm  += partial[((size_t)1 * NCB + cb) * N_ROWS + row];
        sq  += partial[((size_t)2 * NCB + cb) * N_ROWS + row];
    }
    float num  = sm + sq / den;
    float loss = -logf(num / (den + 1e-8f) + 1e-8f);
#pragma unroll
    for (int x = 1; x < 64; x <<= 1) loss += __shfl_xor(loss, x);
    __shared__ float p[4];
    if ((threadIdx.x & 63) == 0) p[threadIdx.x >> 6] = loss;
    __syncthreads();
    if (threadIdx.x == 0) blocksum[blockIdx.x] = p[0] + p[1] + p[2] + p[3];
}

__global__ void final_kernel(const float* __restrict__ blocksum, float* __restrict__ out)
{
    float v = (threadIdx.x < 32) ? blocksum[threadIdx.x] : 0.f;
#pragma unroll
    for (int x = 1; x < 64; x <<= 1) v += __shfl_xor(v, x);
    if (threadIdx.x == 0) out[0] = v * (1.0f / (float)N_ROWS);
}

extern "C" void kernel_launch(void* const* d_in, const int* in_sizes, int n_in,
                              void* d_out, int out_size, void* d_ws, size_t ws_size,
                              hipStream_t stream) {
    const float* z1  = (const float*)d_in[0];
    const float* z2  = (const float*)d_in[1];
    const int*   ids = (const int*)d_in[2];

    char* ws = (char*)d_ws;
    unsigned char* z1q = (unsigned char*)ws;                                 // 4 MB
    unsigned char* z2q = (unsigned char*)(ws + (size_t)N_ROWS * DIM);        // 4 MB
    float* partial  = (float*)(ws + (size_t)2 * N_ROWS * DIM);               // 3 MB
    float* blocksum = partial + (size_t)3 * NCB * N_ROWS;                    // 128 B

    norm_cast_kernel<<<dim3(4096), dim3(256), 0, stream>>>(z1, z2, z1q, z2q);
    fused_sim_kernel<<<dim3(1024), dim3(THREADS), 0, stream>>>(z1q, z2q, ids, partial);
    reduce_kernel<<<dim3(32), dim3(256), 0, stream>>>(partial, blocksum);
    final_kernel<<<dim3(1), dim3(64), 0, stream>>>(blocksum, (float*)d_out);
}

// Round 12
// 77.541 us; speedup vs baseline: 1.3428x; 1.0490x over previous
//
#include <hip/hip_runtime.h>
#include <stdint.h>

#define N_ROWS  8192
#define DIM     512            // elements = bytes (fp8)
#define BM      256            // tile M = N = 256
#define BK      64             // K-bytes per tile
#define NTT     8              // K-tiles per super-tile (DIM/BK)
#define NST     4              // super-tiles (by values) per block
#define NG      (NTT * NST)    // 32 flat tiles per block
#define NBUF    4              // LDS ring buffers
#define TB      (BM * BK)      // 16 KB per tile side
#define NCB     32             // j-blocks (8192/256)
#define THREADS 512
#define SCL16   0x7B7B7B7BU    // e8m0 123 = 2^-4 per operand (undoes data x16)

typedef __attribute__((ext_vector_type(16))) float f32x16;
typedef __attribute__((ext_vector_type(8)))  int   i32x8;

#define BAR()    { asm volatile("" ::: "memory"); __builtin_amdgcn_s_barrier(); asm volatile("" ::: "memory"); }
#define WAITV(n) asm volatile("s_waitcnt vmcnt(" #n ")" ::: "memory")
#define WAITL0() asm volatile("s_waitcnt lgkmcnt(0)" ::: "memory")

#define MFMA8(a, b, c) __builtin_amdgcn_mfma_scale_f32_32x32x64_f8f6f4( \
    (a), (b), (c), 0, 0, 0, SCL16, 0, SCL16)

// manual RNE float -> OCP e4m3fn (|f| <= 16 guaranteed; no NaN/inf inputs)
__device__ __forceinline__ unsigned int f2e4m3(float f) {
    unsigned int u = __float_as_uint(f);
    unsigned int s = (u >> 24) & 0x80u;
    float a = fabsf(f);
    if (a < 0.015625f) {                     // subnormal: step 2^-9
        int q = (int)rintf(a * 512.0f);      // 0..8 (8 rolls into min-normal)
        return s | (unsigned int)q;
    }
    unsigned int mag = u & 0x7fffffffu;
    mag += 0x7FFFFu + ((mag >> 20) & 1u);    // RNE into 3-bit mantissa
    return s | ((mag >> 20) - 960u);         // (E-120)<<3 | M3
}

// async global -> LDS, 16 B per lane (wave-uniform LDS base + lane*16)
__device__ __forceinline__ void gload_lds16(const void* g, void* l) {
    __builtin_amdgcn_global_load_lds(
        (const __attribute__((address_space(1))) unsigned int*)g,
        (__attribute__((address_space(3))) unsigned int*)l,
        16, 0, 0);
}

// ---------------- Kernel 1: L2-normalize rows + cast to fp8 (x16) ----------
__global__ __launch_bounds__(256) void norm_cast_kernel(
    const float* __restrict__ z1, const float* __restrict__ z2,
    unsigned char* __restrict__ o1, unsigned char* __restrict__ o2)
{
    int row  = blockIdx.x * 4 + (threadIdx.x >> 6);
    int lane = threadIdx.x & 63;
    const float* src;
    unsigned char* dst;
    if (row < N_ROWS) { src = z1 + (size_t)row * DIM;            dst = o1 + (size_t)row * DIM; }
    else              { src = z2 + (size_t)(row - N_ROWS) * DIM; dst = o2 + (size_t)(row - N_ROWS) * DIM; }

    const float4* s4 = (const float4*)src + lane * 2;
    float4 a = s4[0], b = s4[1];
    float ss = a.x*a.x + a.y*a.y + a.z*a.z + a.w*a.w
             + b.x*b.x + b.y*b.y + b.z*b.z + b.w*b.w;
#pragma unroll
    for (int x = 1; x < 64; x <<= 1) ss += __shfl_xor(ss, x);
    float inv = 16.0f / fmaxf(sqrtf(ss), 1e-12f);   // x16 into e4m3 normal range

    uint2 o;
    o.x = f2e4m3(a.x*inv) | (f2e4m3(a.y*inv) << 8) | (f2e4m3(a.z*inv) << 16) | (f2e4m3(a.w*inv) << 24);
    o.y = f2e4m3(b.x*inv) | (f2e4m3(b.y*inv) << 8) | (f2e4m3(b.z*inv) << 16) | (f2e4m3(b.w*inv) << 24);
    *(uint2*)(dst + lane * 8) = o;
}

// ---------------- Kernel 2: persistent 256x256 MX-fp8 sim GEMM -------------
// Round-6 schedule (best measured) made PERSISTENT: 256 blocks (1/CU), each
// sweeps 4 super-tiles (by values) at fixed bx through ONE flat 32-tile
// pipeline. LDS ring + vmcnt pipeline never drain at super-tile boundaries;
// epilogue overlaps the next super-tile's prefetch. r6's 32B-lane-stride
// frag layout (direct i32x8 ds_read pairs, no v_mov merges).
__global__ __launch_bounds__(THREADS, 2) void fused_sim_kernel(
    const unsigned char* __restrict__ A,    // z1 fp8 [8192][512]
    const unsigned char* __restrict__ B,    // z2 fp8 [8192][512]
    const int* __restrict__ ids,
    float* __restrict__ partial)            // [3][NCB][N_ROWS]
{
    __shared__ alignas(128) unsigned char Js[NBUF][TB];   // 64 KB (J = z2)
    __shared__ alignas(128) unsigned char Is[NBUF][TB];   // 64 KB (I = z1)
    __shared__ int   idj[BM];                             // 1 KB
    __shared__ float red[2][3][BM];                       // 6 KB

    const int tid  = threadIdx.x;
    const int lane = tid & 63;
    const int wid  = tid >> 6;
    const int wr   = wid >> 2;                 // 0..1  (j half: 128 rows, 4 frags)
    const int wc   = wid & 3;                  // 0..3  (i quarter: 64 rows, 2 frags)
    const int li   = lane & 31, lh = lane >> 5;

    // XCD chunking: each XCD owns a 4-wide bx stripe (its z2 slice L2-hot)
    const int flat = blockIdx.x;               // 256 blocks
    const int xcd  = flat & 7;
    const int s    = flat >> 3;                // 0..31
    const int bx   = xcd * 4 + (s & 3);        // 0..31  (j block, fixed)
    const int byg  = s >> 2;                   // 0..7   (i group; 4 by's each)
    const int bcol = bx * BM;

    // per-thread row-ids for st=0 (register, uniform vmcnt) + idj -> LDS
    int rid0 = ids[(size_t)(byg * 4 + 0) * BM + wc * 64 + li];
    int rid1 = ids[(size_t)(byg * 4 + 0) * BM + wc * 64 + 32 + li];
    if (tid < BM) idj[tid] = ids[bcol + tid];

    // stage tile g (16 KB per side, 2 instr/thread/side), r6 layout:
    // seg -> lf=(seg&127)>>1, half=seg&1, fb=seg>>7; LDS addr = seg*16
    // global row = fb*32 + (lf&31), kbyte = (lf>>5)*32 + half*16
    auto stageJ = [&](int g) {
        const int buf = g & 3, k0 = (g & 7) * BK;
#pragma unroll
        for (int gg = 0; gg < 2; ++gg) {
            int seg = gg * 512 + tid;
            int lf = (seg & 127) >> 1, half = seg & 1;
            int row = (seg >> 7) * 32 + (lf & 31);
            int kb  = (lf >> 5) * 32 + half * 16;
            gload_lds16(B + (size_t)(bcol + row) * DIM + k0 + kb, &Js[buf][seg * 16]);
        }
    };
    auto stageI = [&](int g) {
        const int buf = g & 3, k0 = (g & 7) * BK;
        const int brow = (byg * 4 + (g >> 3)) * BM;
#pragma unroll
        for (int gg = 0; gg < 2; ++gg) {
            int seg = gg * 512 + tid;
            int lf = (seg & 127) >> 1, half = seg & 1;
            int row = (seg >> 7) * 32 + (lf & 31);
            int kb  = (lf >> 5) * 32 + half * 16;
            gload_lds16(A + (size_t)(brow + row) * DIM + k0 + kb, &Is[buf][seg * 16]);
        }
    };

    // frag reads: lane-contiguous 32 B (operand row = lane&31,
    // k-bytes = (lane>>5)*32) — direct i32x8, no merge moves (r6 layout)
    auto ldJ = [&](int buf, int jb) -> i32x8 {
        return *(const i32x8*)&Js[buf][((wr * 4 + jb) * 64 + lane) * 32];
    };
    auto ldI = [&](int buf, int ib) -> i32x8 {
        return *(const i32x8*)&Is[buf][((wc * 2 + ib) * 64 + lane) * 32];
    };

    f32x16 acc[4][2];
#pragma unroll
    for (int m = 0; m < 4; ++m)
#pragma unroll
        for (int n = 0; n < 2; ++n) acc[m][n] = (f32x16)0.f;

    i32x8 jf[2][4], iF[2][2];

    // prologue: rid/idj issued above (oldest); stage tiles 0,1
    stageI(0); stageJ(0);
    stageI(1); stageJ(1);
    WAITL0();                      // idj ds_write flushed before BAR
    WAITV(4);                      // rid+idj+tile0 drained; tile1 in flight
    BAR();
    jf[0][0] = ldJ(0, 0); jf[0][1] = ldJ(0, 1);
    iF[0][0] = ldI(0, 0); iF[0][1] = ldI(0, 1);

#pragma unroll
    for (int st = 0; st < NST; ++st) {
        const int brow = (byg * 4 + st) * BM;
#pragma unroll
        for (int t = 0; t < NTT; ++t) {
            const int g = st * NTT + t;
            const int p = g & 1, q = p ^ 1;
            const int cur = g & 3;

            // ---- phase alpha: read j2,j3[g]; stage I(g+2); MFMA (j0,j1)x(i0,i1)
            jf[p][2] = ldJ(cur, 2); jf[p][3] = ldJ(cur, 3);
            if (g + 2 < NG) stageI(g + 2);
            __builtin_amdgcn_s_setprio(1);
            acc[0][0] = MFMA8(jf[p][0], iF[p][0], acc[0][0]);
            acc[0][1] = MFMA8(jf[p][0], iF[p][1], acc[0][1]);
            acc[1][0] = MFMA8(jf[p][1], iF[p][0], acc[1][0]);
            acc[1][1] = MFMA8(jf[p][1], iF[p][1], acc[1][1]);
            __builtin_amdgcn_s_setprio(0);

            // ---- phase beta: counted wait, read g+1 front frags, stage J(g+2),
            //      MFMA (j2,j3)x(i0,i1)
            if (g < NG - 2) { WAITV(2); } else { WAITV(0); }
            BAR();
            if (g + 1 < NG) {
                const int nxt = (g + 1) & 3;
                jf[q][0] = ldJ(nxt, 0); jf[q][1] = ldJ(nxt, 1);
                iF[q][0] = ldI(nxt, 0); iF[q][1] = ldI(nxt, 1);
            }
            if (g + 2 < NG) stageJ(g + 2);
            __builtin_amdgcn_s_setprio(1);
            acc[2][0] = MFMA8(jf[p][2], iF[p][0], acc[2][0]);
            acc[2][1] = MFMA8(jf[p][2], iF[p][1], acc[2][1]);
            acc[3][0] = MFMA8(jf[p][3], iF[p][0], acc[3][0]);
            acc[3][1] = MFMA8(jf[p][3], iF[p][1], acc[3][1]);
            __builtin_amdgcn_s_setprio(0);
        }

        // ---- per-super-tile epilogue (overlaps st+1's in-flight prefetch)
        // 32x32 C/D: col(i)=lane&31, row(j)=(reg&3)+8*(reg>>2)+4*(lane>>5)
        float dp0 = 0.f, sp0 = 0.f, qp0 = 0.f, dp1 = 0.f, sp1 = 0.f, qp1 = 0.f;
#pragma unroll
        for (int jb = 0; jb < 4; ++jb) {
#pragma unroll
            for (int reg = 0; reg < 16; ++reg) {
                int j   = wr * 128 + jb * 32 + (reg & 3) + 8 * (reg >> 2) + 4 * lh;
                int cid = idj[j];
                float v0 = acc[jb][0][reg], v1 = acc[jb][1][reg];
                float e0 = __expf(v0 * 10.0f - 10.0f);   // exp(sim - 10)
                float e1 = __expf(v1 * 10.0f - 10.0f);
                dp0 += e0; dp1 += e1;
                sp0 += (rid0 == cid) ? e0 : 0.f;  qp0 += (rid0 == cid) ? 0.f : e0 * e0;
                sp1 += (rid1 == cid) ? e1 : 0.f;  qp1 += (rid1 == cid) ? 0.f : e1 * e1;
            }
        }
        dp0 += __shfl_xor(dp0, 32); sp0 += __shfl_xor(sp0, 32); qp0 += __shfl_xor(qp0, 32);
        dp1 += __shfl_xor(dp1, 32); sp1 += __shfl_xor(sp1, 32); qp1 += __shfl_xor(qp1, 32);
        if (lane < 32) {
            red[wr][0][wc * 64 + li]      = dp0;
            red[wr][1][wc * 64 + li]      = sp0;
            red[wr][2][wc * 64 + li]      = qp0;
            red[wr][0][wc * 64 + 32 + li] = dp1;
            red[wr][1][wc * 64 + 32 + li] = sp1;
            red[wr][2][wc * 64 + 32 + li] = qp1;
        }
        WAITL0();
        BAR();
        if (tid < BM) {
#pragma unroll
            for (int s2 = 0; s2 < 3; ++s2) {
                float v = red[0][s2][tid] + red[1][s2][tid];
                partial[((size_t)s2 * NCB + bx) * N_ROWS + brow + tid] = v;
            }
        }
        if (st + 1 < NST) {
            rid0 = ids[(size_t)(byg * 4 + st + 1) * BM + wc * 64 + li];
            rid1 = ids[(size_t)(byg * 4 + st + 1) * BM + wc * 64 + 32 + li];
            // drain stores+rid (and any matured prefetch); pipeline resumes
            WAITV(0);
            BAR();
#pragma unroll
            for (int m = 0; m < 4; ++m)
#pragma unroll
                for (int n = 0; n < 2; ++n) acc[m][n] = (f32x16)0.f;
        }
    }
}

// ---------------- Kernel 3: per-row loss, per-block sums ----------------
__global__ __launch_bounds__(256) void reduce_kernel(
    const float* __restrict__ partial, float* __restrict__ blocksum)
{
    int row = blockIdx.x * 256 + threadIdx.x;
    float den = 0.f, sm = 0.f, sq = 0.f;
#pragma unroll 4
    for (int cb = 0; cb < NCB; ++cb) {
        den += partial[((size_t)0 * NCB + cb) * N_ROWS + row];
        sm  += partial[((size_t)1 * NCB + cb) * N_ROWS + row];
        sq  += partial[((size_t)2 * NCB + cb) * N_ROWS + row];
    }
    float num  = sm + sq / den;
    float loss = -logf(num / (den + 1e-8f) + 1e-8f);
#pragma unroll
    for (int x = 1; x < 64; x <<= 1) loss += __shfl_xor(loss, x);
    __shared__ float p[4];
    if ((threadIdx.x & 63) == 0) p[threadIdx.x >> 6] = loss;
    __syncthreads();
    if (threadIdx.x == 0) blocksum[blockIdx.x] = p[0] + p[1] + p[2] + p[3];
}

__global__ void final_kernel(const float* __restrict__ blocksum, float* __restrict__ out)
{
    float v = (threadIdx.x < 32) ? blocksum[threadIdx.x] : 0.f;
#pragma unroll
    for (int x = 1; x < 64; x <<= 1) v += __shfl_xor(v, x);
    if (threadIdx.x == 0) out[0] = v * (1.0f / (float)N_ROWS);
}

extern "C" void kernel_launch(void* const* d_in, const int* in_sizes, int n_in,
                              void* d_out, int out_size, void* d_ws, size_t ws_size,
                              hipStream_t stream) {
    const float* z1  = (const float*)d_in[0];
    const float* z2  = (const float*)d_in[1];
    const int*   ids = (const int*)d_in[2];

    char* ws = (char*)d_ws;
    unsigned char* z1q = (unsigned char*)ws;                                 // 4 MB
    unsigned char* z2q = (unsigned char*)(ws + (size_t)N_ROWS * DIM);        // 4 MB
    float* partial  = (float*)(ws + (size_t)2 * N_ROWS * DIM);               // 3 MB
    float* blocksum = partial + (size_t)3 * NCB * N_ROWS;                    // 128 B

    norm_cast_kernel<<<dim3(4096), dim3(256), 0, stream>>>(z1, z2, z1q, z2q);
    fused_sim_kernel<<<dim3(256), dim3(THREADS), 0, stream>>>(z1q, z2q, ids, partial);
    reduce_kernel<<<dim3(32), dim3(256), 0, stream>>>(partial, blocksum);
    final_kernel<<<dim3(1), dim3(64), 0, stream>>>(blocksum, (float*)d_out);
}